// Round 1
// baseline (6780.222 us; speedup 1.0000x reference)
//
#include <hip/hip_runtime.h>
#include <hip/hip_bf16.h>

// Problem constants
#define B_    32
#define S_    16
#define L_    64
#define E_    300
#define P_    100
#define H_    256
#define DATT  612
#define NS    512      // B*S
#define M1    32768    // NS*L
#define G4H   1024     // 4*H

typedef __hip_bfloat16 bf16;

__device__ __forceinline__ float b2f(bf16 v) { return __bfloat162float(v); }
__device__ __forceinline__ bf16  f2b(float v) { return __float2bfloat16(v); }
__device__ __forceinline__ float sigm(float x) { return 1.0f / (1.0f + __expf(-x)); }
__device__ __forceinline__ float tanh_f(float x) {
    // tanh(x) = 1 - 2/(e^{2x}+1) ; fine for our small magnitudes, saturates correctly
    return 1.0f - 2.0f / (__expf(2.0f * x) + 1.0f);
}

// ---------------------------------------------------------------------------
// K0a: transpose + bf16-cast the 4 Whh matrices [1024,256] -> [256,1024]
// ---------------------------------------------------------------------------
__global__ void k_whhT(const float* __restrict__ w0, const float* __restrict__ w1,
                       const float* __restrict__ w2, const float* __restrict__ w3,
                       bf16* __restrict__ out) {
    const float* w;
    switch (blockIdx.y) { case 0: w = w0; break; case 1: w = w1; break;
                          case 2: w = w2; break; default: w = w3; }
    bf16* o = out + (size_t)blockIdx.y * 256 * 1024;
    int j = blockIdx.x;          // 0..1023 output-gate index
    int k = threadIdx.x;         // 0..255  hidden index
    o[(size_t)k * G4H + j] = f2b(w[(size_t)j * H_ + k]);
}

// ---------------------------------------------------------------------------
// K0b: gather x = [emb[tok] | wpe[wpos]]  -> bf16 [32768, 400]
// ---------------------------------------------------------------------------
__global__ void k_gather_x(const int* __restrict__ tok, const int* __restrict__ wpos,
                           const float* __restrict__ emb, const float* __restrict__ wpe,
                           bf16* __restrict__ x) {
    int i = blockIdx.x;
    int t = tok[i], p = wpos[i];
    const float* er = emb + (size_t)t * E_;
    const float* pr = wpe + (size_t)p * P_;
    bf16* xr = x + (size_t)i * 400;
    for (int c = threadIdx.x; c < 400; c += blockDim.x)
        xr[c] = f2b(c < E_ ? er[c] : pr[c - E_]);
}

// ---------------------------------------------------------------------------
// K1: C[i, colOff+n] = bf16( sum_k A[i,k]*W[n,k] + bias[n] )
// A bf16 [M, lda], W f32 [1024, K] row-major, C bf16 ldc.
// BM=BN=64, BK=32, 256 threads, 4x4 microtile.
// ---------------------------------------------------------------------------
__global__ __launch_bounds__(256) void k_gemm_g(const bf16* __restrict__ A, int lda, int K,
                                                const float* __restrict__ W,
                                                const float* __restrict__ bias,
                                                bf16* __restrict__ C, int ldc, int colOff) {
    __shared__ float As[32][68];
    __shared__ float Bs[32][68];
    int tid = threadIdx.x;
    int tx = tid & 15, ty = tid >> 4;
    int i0 = blockIdx.y * 64, n0 = blockIdx.x * 64;
    float acc[4][4] = {};
    int nkt = (K + 31) / 32;
    for (int kt = 0; kt < nkt; ++kt) {
        int k0 = kt * 32;
        {   // A: consecutive lanes -> consecutive k (coalesced)
            int kk = tid & 31, mB = tid >> 5;
            #pragma unroll
            for (int l = 0; l < 8; ++l) {
                int m = mB + l * 8;
                int k = k0 + kk;
                As[kk][m] = (k < K) ? b2f(A[(size_t)(i0 + m) * lda + k]) : 0.f;
            }
        }
        {   // W: consecutive lanes -> consecutive k within row n (coalesced)
            int n = tid & 63, kB = tid >> 6;
            #pragma unroll
            for (int l = 0; l < 8; ++l) {
                int kk = kB + l * 4;
                int k = k0 + kk;
                Bs[kk][n] = (k < K) ? W[(size_t)(n0 + n) * K + k] : 0.f;
            }
        }
        __syncthreads();
        #pragma unroll
        for (int kk = 0; kk < 32; ++kk) {
            float a[4], b[4];
            #pragma unroll
            for (int i = 0; i < 4; ++i) a[i] = As[kk][ty * 4 + i];
            #pragma unroll
            for (int j = 0; j < 4; ++j) b[j] = Bs[kk][tx * 4 + j];
            #pragma unroll
            for (int i = 0; i < 4; ++i)
                #pragma unroll
                for (int j = 0; j < 4; ++j) acc[i][j] += a[i] * b[j];
        }
        __syncthreads();
    }
    #pragma unroll
    for (int i = 0; i < 4; ++i) {
        size_t r = (size_t)(i0 + ty * 4 + i);
        #pragma unroll
        for (int j = 0; j < 4; ++j) {
            int n = n0 + tx * 4 + j;
            C[r * ldc + colOff + n] = f2b(acc[i][j] + bias[n]);
        }
    }
}

// ---------------------------------------------------------------------------
// K2: LSTM recurrence. One block = G=4 sequences of one direction (blockIdx.y).
// g (bf16, includes bias) [seq*T + t, 2048]; whhT bf16 [dir][256][1024];
// out f32 [seq*T + t, 512] at column dir*256. Optional final h -> finalh.
// ---------------------------------------------------------------------------
__global__ __launch_bounds__(256) void k_lstm(const bf16* __restrict__ g, int ldg,
                                              const bf16* __restrict__ whhT_base,
                                              float* __restrict__ out, int ldo,
                                              float* __restrict__ finalh, int fstride,
                                              int T) {
    __shared__ __align__(16) float h_lds[256][4];   // [unit][seq]
    __shared__ float gates[4][1024];                // [seq][gate]
    int tid = threadIdx.x;
    int dir = blockIdx.y;
    const bf16* whhT = whhT_base + (size_t)dir * 256 * 1024;
    int gOff = dir * 1024;
    int oOff = dir * 256;
    int reverse = dir;
    int seq0 = blockIdx.x * 4;
    float c0 = 0.f, c1 = 0.f, c2 = 0.f, c3 = 0.f;
    #pragma unroll
    for (int s = 0; s < 4; ++s) h_lds[tid][s] = 0.f;
    __syncthreads();
    for (int t = 0; t < T; ++t) {
        int ti = reverse ? (T - 1 - t) : t;
        // phase A: gates = g_pre + h @ Whh^T
        #pragma unroll
        for (int jb = 0; jb < 4; ++jb) {
            int j = jb * 256 + tid;
            float a0 = b2f(g[((size_t)(seq0 + 0) * T + ti) * ldg + gOff + j]);
            float a1 = b2f(g[((size_t)(seq0 + 1) * T + ti) * ldg + gOff + j]);
            float a2 = b2f(g[((size_t)(seq0 + 2) * T + ti) * ldg + gOff + j]);
            float a3 = b2f(g[((size_t)(seq0 + 3) * T + ti) * ldg + gOff + j]);
            const bf16* wc = whhT + j;
            #pragma unroll 4
            for (int k = 0; k < 256; ++k) {
                float4 hv = *(const float4*)(&h_lds[k][0]);   // broadcast
                float w = b2f(wc[k * 1024]);
                a0 += hv.x * w; a1 += hv.y * w; a2 += hv.z * w; a3 += hv.w * w;
            }
            gates[0][j] = a0; gates[1][j] = a1; gates[2][j] = a2; gates[3][j] = a3;
        }
        __syncthreads();
        // phase B: elementwise cell update; thread owns unit tid for all 4 seqs
        float hn[4];
        {
            float ig, fg, gg, og;
            ig = sigm(gates[0][tid]);       fg = sigm(gates[0][256 + tid]);
            gg = tanh_f(gates[0][512 + tid]); og = sigm(gates[0][768 + tid]);
            c0 = fg * c0 + ig * gg; hn[0] = og * tanh_f(c0);
            ig = sigm(gates[1][tid]);       fg = sigm(gates[1][256 + tid]);
            gg = tanh_f(gates[1][512 + tid]); og = sigm(gates[1][768 + tid]);
            c1 = fg * c1 + ig * gg; hn[1] = og * tanh_f(c1);
            ig = sigm(gates[2][tid]);       fg = sigm(gates[2][256 + tid]);
            gg = tanh_f(gates[2][512 + tid]); og = sigm(gates[2][768 + tid]);
            c2 = fg * c2 + ig * gg; hn[2] = og * tanh_f(c2);
            ig = sigm(gates[3][tid]);       fg = sigm(gates[3][256 + tid]);
            gg = tanh_f(gates[3][512 + tid]); og = sigm(gates[3][768 + tid]);
            c3 = fg * c3 + ig * gg; hn[3] = og * tanh_f(c3);
        }
        __syncthreads();   // all phase-A reads of old h done before overwrite
        #pragma unroll
        for (int s = 0; s < 4; ++s) {
            h_lds[tid][s] = hn[s];
            out[((size_t)(seq0 + s) * T + ti) * ldo + oOff + tid] = hn[s];
        }
        __syncthreads();
    }
    if (finalh) {
        #pragma unroll
        for (int s = 0; s < 4; ++s)
            finalh[(size_t)(seq0 + s) * fstride + dir * 256 + tid] = h_lds[tid][s];
    }
}

// ---------------------------------------------------------------------------
// K3: attention scores: score[i] = proj . tanh( z[i] @ W + bias )
// z = [ hsrc[i, 0:512] | pos[i, 0:100] ]
// mode 0 (word): pos from x_bf[i, 300:400] (bf16)
// mode 1 (sent): pos = spe_tab[spos[i]]    (f32)
// ---------------------------------------------------------------------------
__global__ __launch_bounds__(256) void k_attn_score(const float* __restrict__ hsrc,
        const bf16* __restrict__ xpos, const float* __restrict__ spe,
        const int* __restrict__ spos,
        const float* __restrict__ W, const float* __restrict__ bias,
        const float* __restrict__ proj, float* __restrict__ score, int mode) {
    __shared__ float As[32][68];
    __shared__ float Bs[32][68];
    int tid = threadIdx.x;
    int tx = tid & 15, ty = tid >> 4;
    int i0 = blockIdx.x * 64;
    float srow[4] = {0.f, 0.f, 0.f, 0.f};
    for (int n0 = 0; n0 < DATT; n0 += 64) {
        float acc[4][4] = {};
        for (int k0 = 0; k0 < DATT; k0 += 32) {
            {
                int kk = tid & 31, mB = tid >> 5;
                #pragma unroll
                for (int l = 0; l < 8; ++l) {
                    int m = mB + l * 8;
                    int row = i0 + m;
                    int k = k0 + kk;
                    float v = 0.f;
                    if (k < 512) v = hsrc[(size_t)row * 512 + k];
                    else if (k < DATT) {
                        int p = k - 512;
                        v = (mode == 0) ? b2f(xpos[(size_t)row * 400 + 300 + p])
                                        : spe[(size_t)spos[row] * P_ + p];
                    }
                    As[kk][m] = v;
                }
            }
            {
                int n = tid & 63, kB = tid >> 6;
                #pragma unroll
                for (int l = 0; l < 8; ++l) {
                    int kk = kB + l * 4;
                    int k = k0 + kk;
                    int nn = n0 + n;
                    Bs[kk][n] = (k < DATT && nn < DATT) ? W[(size_t)k * DATT + nn] : 0.f;
                }
            }
            __syncthreads();
            #pragma unroll
            for (int kk = 0; kk < 32; ++kk) {
                float a[4], b[4];
                #pragma unroll
                for (int i = 0; i < 4; ++i) a[i] = As[kk][ty * 4 + i];
                #pragma unroll
                for (int j = 0; j < 4; ++j) b[j] = Bs[kk][tx * 4 + j];
                #pragma unroll
                for (int i = 0; i < 4; ++i)
                    #pragma unroll
                    for (int j = 0; j < 4; ++j) acc[i][j] += a[i] * b[j];
            }
            __syncthreads();
        }
        // epilogue for this column tile: tanh + proj partial reduce
        #pragma unroll
        for (int j = 0; j < 4; ++j) {
            int col = n0 + tx * 4 + j;
            if (col < DATT) {
                float bb = bias[col], pp = proj[col];
                #pragma unroll
                for (int i = 0; i < 4; ++i)
                    srow[i] += pp * tanh_f(acc[i][j] + bb);
            }
        }
    }
    // reduce across tx (lanes differing in bits 0..3)
    #pragma unroll
    for (int i = 0; i < 4; ++i) {
        float v = srow[i];
        v += __shfl_xor(v, 1); v += __shfl_xor(v, 2);
        v += __shfl_xor(v, 4); v += __shfl_xor(v, 8);
        if (tx == 0) score[i0 + ty * 4 + i] = v;
    }
}

// ---------------------------------------------------------------------------
// K4: word softmax over L=64 + weighted pool; writes sx = [sen_vec | spe] bf16
// ---------------------------------------------------------------------------
__global__ void k_pool_word(const float* __restrict__ score, const float* __restrict__ sen_out,
                            const float* __restrict__ spe_tab, const int* __restrict__ spos,
                            bf16* __restrict__ sx) {
    int n = blockIdx.x;       // 0..511
    int tid = threadIdx.x;
    __shared__ float a_lds[64];
    if (tid < 64) {
        float sc = score[n * 64 + tid];
        float m = sc;
        #pragma unroll
        for (int off = 32; off >= 1; off >>= 1) m = fmaxf(m, __shfl_xor(m, off));
        float e = __expf(sc - m);
        float s = e;
        #pragma unroll
        for (int off = 32; off >= 1; off >>= 1) s += __shfl_xor(s, off);
        a_lds[tid] = e / s;
    }
    __syncthreads();
    for (int h = tid; h < 512; h += blockDim.x) {
        float acc = 0.f;
        const float* base = sen_out + (size_t)n * 64 * 512 + h;
        #pragma unroll 8
        for (int t = 0; t < 64; ++t) acc += a_lds[t] * base[(size_t)t * 512];
        sx[(size_t)n * DATT + h] = f2b(acc);
    }
    int sp = spos[n];
    for (int p = tid; p < P_; p += blockDim.x)
        sx[(size_t)n * DATT + 512 + p] = f2b(spe_tab[(size_t)sp * P_ + p]);
}

// ---------------------------------------------------------------------------
// K8: sentence softmax over S=16 + pool -> feats[:, 0:512]
// ---------------------------------------------------------------------------
__global__ void k_pool_sent(const float* __restrict__ score, const float* __restrict__ doc_out,
                            float* __restrict__ feats) {
    int n = blockIdx.x;    // 0..31
    int tid = threadIdx.x;
    __shared__ float a_lds[16];
    if (tid < 16) {
        float sc = score[n * 16 + tid];
        float m = sc;
        #pragma unroll
        for (int off = 8; off >= 1; off >>= 1) m = fmaxf(m, __shfl_xor(m, off));
        float e = __expf(sc - m);
        float s = e;
        #pragma unroll
        for (int off = 8; off >= 1; off >>= 1) s += __shfl_xor(s, off);
        a_lds[tid] = e / s;
    }
    __syncthreads();
    for (int h = tid; h < 512; h += blockDim.x) {
        float acc = 0.f;
        const float* base = doc_out + (size_t)n * 16 * 512 + h;
        #pragma unroll
        for (int t = 0; t < 16; ++t) acc += a_lds[t] * base[(size_t)t * 512];
        feats[(size_t)n * 1024 + h] = acc;
    }
}

// ---------------------------------------------------------------------------
// K9: classifier out[b,p] = feats[b] . dense_W[p] + dense_b[p]
// ---------------------------------------------------------------------------
__global__ void k_dense(const float* __restrict__ feats, const float* __restrict__ W,
                        const float* __restrict__ bias, float* __restrict__ out) {
    int b = blockIdx.x, lane = threadIdx.x;
    for (int p = 0; p < 3; ++p) {
        float acc = 0.f;
        for (int k = lane; k < 1024; k += 64)
            acc += feats[(size_t)b * 1024 + k] * W[(size_t)p * 1024 + k];
        #pragma unroll
        for (int off = 32; off >= 1; off >>= 1) acc += __shfl_xor(acc, off);
        if (lane == 0) out[b * 3 + p] = acc + bias[p];
    }
}

// ---------------------------------------------------------------------------
extern "C" void kernel_launch(void* const* d_in, const int* in_sizes, int n_in,
                              void* d_out, int out_size, void* d_ws, size_t ws_size,
                              hipStream_t stream) {
    const int*   tok    = (const int*)d_in[0];
    const int*   wpos   = (const int*)d_in[1];
    const int*   spos   = (const int*)d_in[2];
    const float* emb    = (const float*)d_in[3];
    const float* wpet   = (const float*)d_in[4];
    const float* spet   = (const float*)d_in[5];
    const float* wWih_f = (const float*)d_in[6];
    const float* wWhh_f = (const float*)d_in[7];
    const float* wb_f   = (const float*)d_in[8];
    const float* wWih_b = (const float*)d_in[9];
    const float* wWhh_b = (const float*)d_in[10];
    const float* wb_b   = (const float*)d_in[11];
    const float* sWih_f = (const float*)d_in[12];
    const float* sWhh_f = (const float*)d_in[13];
    const float* sb_f   = (const float*)d_in[14];
    const float* sWih_b = (const float*)d_in[15];
    const float* sWhh_b = (const float*)d_in[16];
    const float* sb_b   = (const float*)d_in[17];
    const float* word_W = (const float*)d_in[18];
    const float* word_bias = (const float*)d_in[19];
    const float* word_proj = (const float*)d_in[20];
    const float* sent_W = (const float*)d_in[21];
    const float* sent_bias = (const float*)d_in[22];
    const float* sent_proj = (const float*)d_in[23];
    const float* dense_W = (const float*)d_in[24];
    const float* dense_b = (const float*)d_in[25];

    char* p = (char*)d_ws;
    auto alloc = [&](size_t bytes) -> void* {
        void* r = (void*)p;
        p += (bytes + 255) & ~(size_t)255;
        return r;
    };
    bf16*  x_bf    = (bf16*) alloc((size_t)M1 * 400 * 2);       // 26.2 MB
    bf16*  g_bf    = (bf16*) alloc((size_t)M1 * 2048 * 2);      // 134.2 MB
    float* sen_out = (float*)alloc((size_t)M1 * 512 * 4);       // 67.1 MB
    float* wscore  = (float*)alloc((size_t)M1 * 4);
    bf16*  sx      = (bf16*) alloc((size_t)NS * DATT * 2);
    bf16*  sg      = (bf16*) alloc((size_t)NS * 2048 * 2);
    float* doc_out = (float*)alloc((size_t)NS * 512 * 4);
    float* sscore  = (float*)alloc((size_t)NS * 4);
    float* feats   = (float*)alloc((size_t)B_ * 1024 * 4);
    bf16*  whhT    = (bf16*) alloc((size_t)4 * 256 * 1024 * 2); // [wf wb sf sb]

    // prep
    k_whhT<<<dim3(1024, 4), 256, 0, stream>>>(wWhh_f, wWhh_b, sWhh_f, sWhh_b, whhT);
    k_gather_x<<<M1, 128, 0, stream>>>(tok, wpos, emb, wpet, x_bf);

    // word-level g = x @ Wih^T + b (both directions into columns 0:1024 / 1024:2048)
    k_gemm_g<<<dim3(16, 512), 256, 0, stream>>>(x_bf, 400, 400, wWih_f, wb_f, g_bf, 2048, 0);
    k_gemm_g<<<dim3(16, 512), 256, 0, stream>>>(x_bf, 400, 400, wWih_b, wb_b, g_bf, 2048, 1024);

    // word-level recurrence (both dirs in one launch)
    k_lstm<<<dim3(128, 2), 256, 0, stream>>>(g_bf, 2048, whhT, sen_out, 512,
                                             nullptr, 0, L_);

    // word attention -> sx = [sen_vec | spe]
    k_attn_score<<<512, 256, 0, stream>>>(sen_out, x_bf, nullptr, nullptr,
                                          word_W, word_bias, word_proj, wscore, 0);
    k_pool_word<<<512, 256, 0, stream>>>(wscore, sen_out, spet, spos, sx);

    // sentence level
    k_gemm_g<<<dim3(16, 8), 256, 0, stream>>>(sx, DATT, DATT, sWih_f, sb_f, sg, 2048, 0);
    k_gemm_g<<<dim3(16, 8), 256, 0, stream>>>(sx, DATT, DATT, sWih_b, sb_b, sg, 2048, 1024);
    k_lstm<<<dim3(8, 2), 256, 0, stream>>>(sg, 2048, whhT + (size_t)2 * 256 * 1024,
                                           doc_out, 512, feats + 512, 1024, S_);

    // sentence attention + pool
    k_attn_score<<<8, 256, 0, stream>>>(doc_out, nullptr, spet, spos,
                                        sent_W, sent_bias, sent_proj, sscore, 1);
    k_pool_sent<<<32, 256, 0, stream>>>(sscore, doc_out, feats);

    // classifier
    k_dense<<<32, 64, 0, stream>>>(feats, dense_W, dense_b, (float*)d_out);
}

// Round 2
// 1443.375 us; speedup vs baseline: 4.6975x; 4.6975x over previous
//
#include <hip/hip_runtime.h>
#include <hip/hip_bf16.h>

// Problem constants
#define B_    32
#define S_    16
#define L_    64
#define E_    300
#define P_    100
#define H_    256
#define DATT  612
#define NS    512      // B*S
#define M1    32768    // NS*L

typedef __hip_bfloat16 hbf;
typedef __attribute__((ext_vector_type(8))) short bf16x8;
typedef __attribute__((ext_vector_type(4))) float f32x4;
typedef __attribute__((ext_vector_type(4))) int i32x4;

__device__ __forceinline__ float u2f(unsigned short u) {
    unsigned int x = ((unsigned int)u) << 16;
    return __builtin_bit_cast(float, x);
}
__device__ __forceinline__ unsigned short f2u(float f) {
    return __builtin_bit_cast(unsigned short, __float2bfloat16(f));
}
__device__ __forceinline__ float sigm(float x) { return 1.0f / (1.0f + __expf(-x)); }
__device__ __forceinline__ float tanh_f(float x) {
    return 1.0f - 2.0f / (__expf(2.0f * x) + 1.0f);
}

// ---------------------------------------------------------------------------
// Prep: Wih concat [2048][Kdst] bf16 (rows 0..1023 fwd, 1024..2047 bwd), 0-pad K
// ---------------------------------------------------------------------------
__global__ void k_prep_wih(const float* __restrict__ wf, const float* __restrict__ wb,
                           int Ksrc, int Kdst, unsigned short* __restrict__ out) {
    int j = blockIdx.x;
    const float* src = (j < 1024) ? (wf + (size_t)j * Ksrc) : (wb + (size_t)(j - 1024) * Ksrc);
    unsigned short* o = out + (size_t)j * Kdst;
    for (int c = threadIdx.x; c < Kdst; c += blockDim.x)
        o[c] = (c < Ksrc) ? f2u(src[c]) : (unsigned short)0;
}

__global__ void k_cat_bias(const float* __restrict__ a, const float* __restrict__ b,
                           float* __restrict__ dst) {
    int i = blockIdx.x * 256 + threadIdx.x;   // 0..2047
    dst[i] = (i < 1024) ? a[i] : b[i - 1024];
}

// whh_sw[d][kt][n][kk] = Whh_d[n][kt*32+kk]  (bf16, fragment-ready)
__global__ void k_prep_whh(const float* __restrict__ w0, const float* __restrict__ w1,
                           const float* __restrict__ w2, const float* __restrict__ w3,
                           unsigned short* __restrict__ out) {
    const float* w;
    switch (blockIdx.y) { case 0: w = w0; break; case 1: w = w1; break;
                          case 2: w = w2; break; default: w = w3; }
    int n = blockIdx.x, tid = threadIdx.x;
    int kt = tid >> 5, kk = tid & 31;
    out[(((size_t)blockIdx.y * 8 + kt) * 1024 + n) * 32 + kk] = f2u(w[(size_t)n * 256 + tid]);
}

// Wt[n][k] = W[k][n], 640x640 zero-padded bf16
__global__ void k_prep_attw(const float* __restrict__ W, unsigned short* __restrict__ out) {
    int n = blockIdx.x;
    for (int k = threadIdx.x; k < 640; k += blockDim.x)
        out[(size_t)n * 640 + k] = (n < DATT && k < DATT) ? f2u(W[(size_t)k * DATT + n]) : (unsigned short)0;
}

// x = [emb[tok] | wpe[wpos] | 0pad] -> bf16 [32768][416]
__global__ void k_gather_x(const int* __restrict__ tok, const int* __restrict__ wpos,
                           const float* __restrict__ emb, const float* __restrict__ wpe,
                           unsigned short* __restrict__ x) {
    int i = blockIdx.x;
    int t = tok[i], p = wpos[i];
    const float* er = emb + (size_t)t * E_;
    const float* pr = wpe + (size_t)p * P_;
    unsigned short* xr = x + (size_t)i * 416;
    for (int c = threadIdx.x; c < 416; c += blockDim.x) {
        float v = (c < E_) ? er[c] : (c < 400 ? pr[c - E_] : 0.f);
        xr[c] = f2u(v);
    }
}

// ---------------------------------------------------------------------------
// MFMA GEMM: C[M][2048] = bf16(A[M][lda] @ W[2048][lda]^T + bias)
// 128x128 tile, BK=32, 256 threads (2x2 waves, each 64x64)
// ---------------------------------------------------------------------------
__global__ __launch_bounds__(256) void k_gemm_bias(
        const unsigned short* __restrict__ A, int lda,
        const unsigned short* __restrict__ W, const float* __restrict__ bias,
        unsigned short* __restrict__ C, int nkt) {
    __shared__ __align__(16) unsigned short As[128][40];
    __shared__ __align__(16) unsigned short Bs[128][40];
    int tid = threadIdx.x;
    int lane = tid & 63, wave = tid >> 6;
    int wm = wave >> 1, wn = wave & 1;
    int i0 = blockIdx.y * 128, n0 = blockIdx.x * 128;
    f32x4 acc[4][4] = {};
    int r = tid >> 2, kc = (tid & 3) * 8;
    for (int kt = 0; kt < nkt; ++kt) {
        int k0 = kt * 32;
        #pragma unroll
        for (int p = 0; p < 2; ++p) {
            int rr = r + p * 64;
            *(i32x4*)&As[rr][kc] = *(const i32x4*)&A[(size_t)(i0 + rr) * lda + k0 + kc];
            *(i32x4*)&Bs[rr][kc] = *(const i32x4*)&W[(size_t)(n0 + rr) * lda + k0 + kc];
        }
        __syncthreads();
        bf16x8 a[4], b[4];
        int arow = wm * 64 + (lane & 15);
        int brow = wn * 64 + (lane & 15);
        int kq = (lane >> 4) * 8;
        #pragma unroll
        for (int mi = 0; mi < 4; ++mi) a[mi] = *(const bf16x8*)&As[arow + mi * 16][kq];
        #pragma unroll
        for (int nj = 0; nj < 4; ++nj) b[nj] = *(const bf16x8*)&Bs[brow + nj * 16][kq];
        #pragma unroll
        for (int mi = 0; mi < 4; ++mi)
            #pragma unroll
            for (int nj = 0; nj < 4; ++nj)
                acc[mi][nj] = __builtin_amdgcn_mfma_f32_16x16x32_bf16(a[mi], b[nj], acc[mi][nj], 0, 0, 0);
        __syncthreads();
    }
    int q = lane >> 4;
    #pragma unroll
    for (int nj = 0; nj < 4; ++nj) {
        int col = n0 + wn * 64 + nj * 16 + (lane & 15);
        float bb = bias[col];
        #pragma unroll
        for (int mi = 0; mi < 4; ++mi)
            #pragma unroll
            for (int rr2 = 0; rr2 < 4; ++rr2) {
                int grow = i0 + wm * 64 + mi * 16 + q * 4 + rr2;
                C[(size_t)grow * 2048 + col] = f2u(acc[mi][nj][rr2] + bb);
            }
    }
}

// ---------------------------------------------------------------------------
// MFMA attention score: score[i] += proj . tanh(z[i] @ W + bias) over 128-col slice
// z = [Hsrc[i,0:512] | pos[i,0:100] | 0]; grid.x = 5 col-blocks, atomicAdd
// ---------------------------------------------------------------------------
__global__ __launch_bounds__(256) void k_attn_mfma(
        const unsigned short* __restrict__ Hsrc,
        const unsigned short* __restrict__ xpos,   // mode0: [M][416], pos at col 300
        const float* __restrict__ spe, const int* __restrict__ spos,  // mode1
        const unsigned short* __restrict__ Wt,     // [640][640] bf16 (n-major)
        const float* __restrict__ bias, const float* __restrict__ proj,
        float* __restrict__ score, int mode) {
    __shared__ __align__(16) unsigned short As[128][40];
    __shared__ __align__(16) unsigned short Bs[128][40];
    int tid = threadIdx.x;
    int lane = tid & 63, wave = tid >> 6;
    int wm = wave >> 1, wn = wave & 1;
    int i0 = blockIdx.y * 128, n0 = blockIdx.x * 128;
    f32x4 acc[4][4] = {};
    int r = tid >> 2, kc = (tid & 3) * 8;
    for (int kt = 0; kt < 20; ++kt) {
        int k0 = kt * 32;
        #pragma unroll
        for (int p = 0; p < 2; ++p) {
            int rr = r + p * 64;
            if (kt < 16) {
                *(i32x4*)&As[rr][kc] = *(const i32x4*)&Hsrc[(size_t)(i0 + rr) * 512 + k0 + kc];
            } else {
                int grow = i0 + rr;
                #pragma unroll
                for (int e = 0; e < 8; ++e) {
                    int k = k0 + kc + e;
                    int pp = k - 512;
                    unsigned short v = 0;
                    if (pp < P_) {
                        if (mode == 0) v = xpos[(size_t)grow * 416 + 300 + pp];
                        else           v = f2u(spe[(size_t)spos[grow] * P_ + pp]);
                    }
                    As[rr][kc + e] = v;
                }
            }
            *(i32x4*)&Bs[rr][kc] = *(const i32x4*)&Wt[(size_t)(n0 + rr) * 640 + k0 + kc];
        }
        __syncthreads();
        bf16x8 a[4], b[4];
        int arow = wm * 64 + (lane & 15);
        int brow = wn * 64 + (lane & 15);
        int kq = (lane >> 4) * 8;
        #pragma unroll
        for (int mi = 0; mi < 4; ++mi) a[mi] = *(const bf16x8*)&As[arow + mi * 16][kq];
        #pragma unroll
        for (int nj = 0; nj < 4; ++nj) b[nj] = *(const bf16x8*)&Bs[brow + nj * 16][kq];
        #pragma unroll
        for (int mi = 0; mi < 4; ++mi)
            #pragma unroll
            for (int nj = 0; nj < 4; ++nj)
                acc[mi][nj] = __builtin_amdgcn_mfma_f32_16x16x32_bf16(a[mi], b[nj], acc[mi][nj], 0, 0, 0);
        __syncthreads();
    }
    float srow[4][4] = {};
    int q = lane >> 4;
    #pragma unroll
    for (int nj = 0; nj < 4; ++nj) {
        int col = n0 + wn * 64 + nj * 16 + (lane & 15);
        if (col < DATT) {
            float bb = bias[col], pp = proj[col];
            #pragma unroll
            for (int mi = 0; mi < 4; ++mi)
                #pragma unroll
                for (int rr2 = 0; rr2 < 4; ++rr2)
                    srow[mi][rr2] += pp * tanh_f(acc[mi][nj][rr2] + bb);
        }
    }
    #pragma unroll
    for (int mi = 0; mi < 4; ++mi)
        #pragma unroll
        for (int rr2 = 0; rr2 < 4; ++rr2) {
            float v = srow[mi][rr2];
            v += __shfl_xor(v, 1); v += __shfl_xor(v, 2);
            v += __shfl_xor(v, 4); v += __shfl_xor(v, 8);
            if ((lane & 15) == 0)
                atomicAdd(&score[i0 + wm * 64 + mi * 16 + q * 4 + rr2], v);
        }
}

// ---------------------------------------------------------------------------
// MFMA LSTM: one block = 16 sequences of one direction.
// gates[16][1024] = gpre + h[16][256] @ WhhT, weights streamed fragment-ready.
// ---------------------------------------------------------------------------
__global__ __launch_bounds__(256) void k_lstm_mfma(
        const unsigned short* __restrict__ g,    // [(seq)*T+t][2048] bf16 (bias folded)
        const unsigned short* __restrict__ whh,  // [2][8][1024][32] bf16
        unsigned short* __restrict__ out,        // [(seq)*T+t][512] bf16
        float* __restrict__ finalh,              // optional, stride 1024
        int T) {
    __shared__ __align__(16) unsigned short h_lds[16][264];   // pad 256->264
    __shared__ __align__(16) float gates[16][1028];           // pad 1024->1028
    __shared__ __align__(16) unsigned short gpre[16][1024];
    int tid = threadIdx.x;
    int lane = tid & 63;
    int w = tid >> 6;                 // wave -> gate cols [w*256, w*256+256)
    int dir = blockIdx.y;
    int seq0 = blockIdx.x * 16;
    const unsigned short* wh = whh + (size_t)dir * 8 * 1024 * 32;

    float c[16];
    #pragma unroll
    for (int s = 0; s < 16; ++s) c[s] = 0.f;
    for (int i = tid; i < 16 * 264; i += 256) ((unsigned short*)h_lds)[i] = 0;
    __syncthreads();

    int u = tid;                      // unit for nonlinearity
    for (int t = 0; t < T; ++t) {
        int ti = dir ? (T - 1 - t) : t;
        // (a) issue g_pre loads early (consumed after MFMA phase)
        i32x4 gst[8];
        #pragma unroll
        for (int m = 0; m < 8; ++m) {
            int Bb = m * 4096 + tid * 16;          // byte offset in gpre
            int s = Bb >> 11;
            int colb = Bb & 2047;
            gst[m] = *(const i32x4*)(g + ((size_t)(seq0 + s) * T + ti) * 2048
                                       + dir * 1024 + (colb >> 1));
        }
        // (b) A fragments from h_lds
        bf16x8 a[8];
        int arow = lane & 15;
        int kq = (lane >> 4) * 8;
        #pragma unroll
        for (int kt = 0; kt < 8; ++kt)
            a[kt] = *(const bf16x8*)&h_lds[arow][kt * 32 + kq];
        // (c) MFMA over 16 n-frags, ping-pong B prefetch from L2
        int ncol = w * 256 + (lane & 15);
        bf16x8 b0[8], b1[8];
        #pragma unroll
        for (int kt = 0; kt < 8; ++kt)
            b0[kt] = *(const bf16x8*)&wh[((size_t)kt * 1024 + ncol) * 32 + kq];
        #pragma unroll
        for (int ni = 0; ni < 16; ++ni) {
            if (ni + 1 < 16) {
                int nc = ncol + (ni + 1) * 16;
                if (ni & 1) {
                    #pragma unroll
                    for (int kt = 0; kt < 8; ++kt)
                        b0[kt] = *(const bf16x8*)&wh[((size_t)kt * 1024 + nc) * 32 + kq];
                } else {
                    #pragma unroll
                    for (int kt = 0; kt < 8; ++kt)
                        b1[kt] = *(const bf16x8*)&wh[((size_t)kt * 1024 + nc) * 32 + kq];
                }
            }
            f32x4 acc = {0.f, 0.f, 0.f, 0.f};
            if (ni & 1) {
                #pragma unroll
                for (int kt = 0; kt < 8; ++kt)
                    acc = __builtin_amdgcn_mfma_f32_16x16x32_bf16(a[kt], b1[kt], acc, 0, 0, 0);
            } else {
                #pragma unroll
                for (int kt = 0; kt < 8; ++kt)
                    acc = __builtin_amdgcn_mfma_f32_16x16x32_bf16(a[kt], b0[kt], acc, 0, 0, 0);
            }
            int col = ncol + ni * 16;
            int srow = (lane >> 4) * 4;
            #pragma unroll
            for (int rr = 0; rr < 4; ++rr)
                gates[srow + rr][col] = acc[rr];
        }
        // (d) park g_pre in LDS (lane-linear, conflict-free)
        #pragma unroll
        for (int m = 0; m < 8; ++m) {
            int Bb = m * 4096 + tid * 16;
            *(i32x4*)((char*)&gpre[0][0] + Bb) = gst[m];
        }
        __syncthreads();
        // (e) cell update: thread owns unit u for all 16 seqs
        bool last = (t == T - 1);
        #pragma unroll
        for (int s = 0; s < 16; ++s) {
            float ig = gates[s][u]       + u2f(gpre[s][u]);
            float fg = gates[s][256 + u] + u2f(gpre[s][256 + u]);
            float gg = gates[s][512 + u] + u2f(gpre[s][512 + u]);
            float og = gates[s][768 + u] + u2f(gpre[s][768 + u]);
            ig = sigm(ig); fg = sigm(fg); gg = tanh_f(gg); og = sigm(og);
            c[s] = fg * c[s] + ig * gg;
            float hn = og * tanh_f(c[s]);
            h_lds[s][u] = f2u(hn);
            out[((size_t)(seq0 + s) * T + ti) * 512 + dir * 256 + u] = f2u(hn);
            if (last && finalh)
                finalh[(size_t)(seq0 + s) * 1024 + dir * 256 + u] = hn;
        }
        __syncthreads();
    }
}

// ---------------------------------------------------------------------------
// word softmax over L=64 + pool -> sx = [sen_vec | spe | 0] bf16 [512][640]
// ---------------------------------------------------------------------------
__global__ void k_pool_word(const float* __restrict__ score, const unsigned short* __restrict__ sen_out,
                            const float* __restrict__ spe, const int* __restrict__ spos,
                            unsigned short* __restrict__ sx) {
    int n = blockIdx.x, tid = threadIdx.x;
    __shared__ float a_lds[64];
    if (tid < 64) {
        float sc = score[n * 64 + tid];
        float m = sc;
        #pragma unroll
        for (int off = 32; off >= 1; off >>= 1) m = fmaxf(m, __shfl_xor(m, off));
        float e = __expf(sc - m);
        float s = e;
        #pragma unroll
        for (int off = 32; off >= 1; off >>= 1) s += __shfl_xor(s, off);
        a_lds[tid] = e / s;
    }
    __syncthreads();
    for (int h = tid; h < 512; h += blockDim.x) {
        float acc = 0.f;
        const unsigned short* base = sen_out + (size_t)n * 64 * 512 + h;
        #pragma unroll 8
        for (int t = 0; t < 64; ++t) acc += a_lds[t] * u2f(base[(size_t)t * 512]);
        sx[(size_t)n * 640 + h] = f2u(acc);
    }
    int sp = spos[n];
    for (int p2 = tid; p2 < 128; p2 += blockDim.x)
        sx[(size_t)n * 640 + 512 + p2] = (p2 < P_) ? f2u(spe[(size_t)sp * P_ + p2]) : (unsigned short)0;
}

// sentence softmax over S=16 + pool -> feats[:, 0:512]
__global__ void k_pool_sent(const float* __restrict__ score, const unsigned short* __restrict__ doc_out,
                            float* __restrict__ feats) {
    int n = blockIdx.x, tid = threadIdx.x;
    __shared__ float a_lds[16];
    if (tid < 16) {
        float sc = score[n * 16 + tid];
        float m = sc;
        #pragma unroll
        for (int off = 8; off >= 1; off >>= 1) m = fmaxf(m, __shfl_xor(m, off));
        float e = __expf(sc - m);
        float s = e;
        #pragma unroll
        for (int off = 8; off >= 1; off >>= 1) s += __shfl_xor(s, off);
        a_lds[tid] = e / s;
    }
    __syncthreads();
    for (int h = tid; h < 512; h += blockDim.x) {
        float acc = 0.f;
        const unsigned short* base = doc_out + (size_t)n * 16 * 512 + h;
        #pragma unroll
        for (int t = 0; t < 16; ++t) acc += a_lds[t] * u2f(base[(size_t)t * 512]);
        feats[(size_t)n * 1024 + h] = acc;
    }
}

__global__ void k_dense(const float* __restrict__ feats, const float* __restrict__ W,
                        const float* __restrict__ bias, float* __restrict__ out) {
    int b = blockIdx.x, lane = threadIdx.x;
    for (int p = 0; p < 3; ++p) {
        float acc = 0.f;
        for (int k = lane; k < 1024; k += 64)
            acc += feats[(size_t)b * 1024 + k] * W[(size_t)p * 1024 + k];
        #pragma unroll
        for (int off = 32; off >= 1; off >>= 1) acc += __shfl_xor(acc, off);
        if (lane == 0) out[b * 3 + p] = acc + bias[p];
    }
}

// ---------------------------------------------------------------------------
extern "C" void kernel_launch(void* const* d_in, const int* in_sizes, int n_in,
                              void* d_out, int out_size, void* d_ws, size_t ws_size,
                              hipStream_t stream) {
    const int*   tok    = (const int*)d_in[0];
    const int*   wpos   = (const int*)d_in[1];
    const int*   spos   = (const int*)d_in[2];
    const float* emb    = (const float*)d_in[3];
    const float* wpet   = (const float*)d_in[4];
    const float* spet   = (const float*)d_in[5];
    const float* wWih_f = (const float*)d_in[6];
    const float* wWhh_f = (const float*)d_in[7];
    const float* wb_f   = (const float*)d_in[8];
    const float* wWih_b = (const float*)d_in[9];
    const float* wWhh_b = (const float*)d_in[10];
    const float* wb_b   = (const float*)d_in[11];
    const float* sWih_f = (const float*)d_in[12];
    const float* sWhh_f = (const float*)d_in[13];
    const float* sb_f   = (const float*)d_in[14];
    const float* sWih_b = (const float*)d_in[15];
    const float* sWhh_b = (const float*)d_in[16];
    const float* sb_b   = (const float*)d_in[17];
    const float* word_W = (const float*)d_in[18];
    const float* word_bias = (const float*)d_in[19];
    const float* word_proj = (const float*)d_in[20];
    const float* sent_W = (const float*)d_in[21];
    const float* sent_bias = (const float*)d_in[22];
    const float* sent_proj = (const float*)d_in[23];
    const float* dense_W = (const float*)d_in[24];
    const float* dense_b = (const float*)d_in[25];

    char* p = (char*)d_ws;
    auto alloc = [&](size_t bytes) -> void* {
        void* r = (void*)p;
        p += (bytes + 255) & ~(size_t)255;
        return r;
    };
    unsigned short* x_bf    = (unsigned short*)alloc((size_t)M1 * 416 * 2);
    unsigned short* g_bf    = (unsigned short*)alloc((size_t)M1 * 2048 * 2);
    unsigned short* sen_out = (unsigned short*)alloc((size_t)M1 * 512 * 2);
    float*          scores  = (float*)alloc((size_t)(M1 + NS) * 4);   // wscore | sscore
    unsigned short* sx      = (unsigned short*)alloc((size_t)NS * 640 * 2);
    unsigned short* sg      = (unsigned short*)alloc((size_t)NS * 2048 * 2);
    unsigned short* doc_out = (unsigned short*)alloc((size_t)NS * 512 * 2);
    float*          feats   = (float*)alloc((size_t)B_ * 1024 * 4);
    unsigned short* wih_w   = (unsigned short*)alloc((size_t)2048 * 416 * 2);
    unsigned short* wih_s   = (unsigned short*)alloc((size_t)2048 * 640 * 2);
    float*          bias_w  = (float*)alloc(2048 * 4);
    float*          bias_s  = (float*)alloc(2048 * 4);
    unsigned short* whh_sw  = (unsigned short*)alloc((size_t)4 * 8 * 1024 * 32 * 2);
    unsigned short* attw_w  = (unsigned short*)alloc((size_t)640 * 640 * 2);
    unsigned short* attw_s  = (unsigned short*)alloc((size_t)640 * 640 * 2);
    float* wscore = scores;
    float* sscore = scores + M1;

    // ---- prep (all independent) ----
    hipMemsetAsync(scores, 0, (size_t)(M1 + NS) * 4, stream);
    k_prep_wih<<<2048, 256, 0, stream>>>(wWih_f, wWih_b, 400, 416, wih_w);
    k_prep_wih<<<2048, 256, 0, stream>>>(sWih_f, sWih_b, 612, 640, wih_s);
    k_cat_bias<<<8, 256, 0, stream>>>(wb_f, wb_b, bias_w);
    k_cat_bias<<<8, 256, 0, stream>>>(sb_f, sb_b, bias_s);
    k_prep_whh<<<dim3(1024, 4), 256, 0, stream>>>(wWhh_f, wWhh_b, sWhh_f, sWhh_b, whh_sw);
    k_prep_attw<<<640, 256, 0, stream>>>(word_W, attw_w);
    k_prep_attw<<<640, 256, 0, stream>>>(sent_W, attw_s);
    k_gather_x<<<M1, 256, 0, stream>>>(tok, wpos, emb, wpet, x_bf);

    // ---- word level ----
    k_gemm_bias<<<dim3(16, 256), 256, 0, stream>>>(x_bf, 416, wih_w, bias_w, g_bf, 13);
    k_lstm_mfma<<<dim3(32, 2), 256, 0, stream>>>(g_bf, whh_sw, sen_out, nullptr, L_);
    k_attn_mfma<<<dim3(5, 256), 256, 0, stream>>>(sen_out, x_bf, nullptr, nullptr,
                                                  attw_w, word_bias, word_proj, wscore, 0);
    k_pool_word<<<512, 256, 0, stream>>>(wscore, sen_out, spet, spos, sx);

    // ---- sentence level ----
    k_gemm_bias<<<dim3(16, 4), 256, 0, stream>>>(sx, 640, wih_s, bias_s, sg, 20);
    k_lstm_mfma<<<dim3(2, 2), 256, 0, stream>>>(sg, whh_sw + (size_t)2 * 8 * 1024 * 32,
                                                doc_out, feats + 512, S_);
    k_attn_mfma<<<dim3(5, 4), 256, 0, stream>>>(doc_out, nullptr, spet, spos,
                                                attw_s, sent_bias, sent_proj, sscore, 1);
    k_pool_sent<<<32, 256, 0, stream>>>(sscore, doc_out, feats);

    // ---- classifier ----
    k_dense<<<32, 64, 0, stream>>>(feats, dense_W, dense_b, (float*)d_out);
}